// Round 2
// baseline (246.228 us; speedup 1.0000x reference)
//
#include <hip/hip_runtime.h>
#include <hip/hip_bf16.h>
#include <stdint.h>

typedef __bf16 bf16;
typedef __bf16 bf16x8 __attribute__((ext_vector_type(8)));
typedef float  f32x4  __attribute__((ext_vector_type(4)));
typedef unsigned short u16;
typedef unsigned int   u32;

#define S_LEN 1536
#define NDIM  1024
#define MROWS 3072

__device__ __forceinline__ float b2f(u16 u){
  union { u32 i; float f; } v; v.i = ((u32)u) << 16; return v.f;
}
__device__ __forceinline__ u16 f2b(float f){
  u32 x = __builtin_bit_cast(u32, f);
  u32 r = x + 0x7fffu + ((x >> 16) & 1u);
  return (u16)(r >> 16);
}

// ---------------------------------------------------------------------------
// Cast fp32 -> bf16, 8 elems/thread.
// ---------------------------------------------------------------------------
__global__ __launch_bounds__(256) void cast_f32_bf16(
    const float* __restrict__ in, u16* __restrict__ out)
{
  const int i = blockIdx.x * 256 + threadIdx.x;   // handles elems [8i, 8i+8)
  const float4* p = (const float4*)in;
  float4 a = p[i*2], b = p[i*2+1];
  alignas(16) u16 tmp[8];
  tmp[0]=f2b(a.x); tmp[1]=f2b(a.y); tmp[2]=f2b(a.z); tmp[3]=f2b(a.w);
  tmp[4]=f2b(b.x); tmp[5]=f2b(b.y); tmp[6]=f2b(b.z); tmp[7]=f2b(b.w);
  *(uint4*)(out + (size_t)i*8) = *(const uint4*)tmp;
}

// ---------------------------------------------------------------------------
// Transpose 4 fp32 [1024][1024] matrices -> bf16 WT[n][k] so GEMM B-fragments
// are contiguous in k (ds_read_b128 instead of strided u16 reads).
// ---------------------------------------------------------------------------
__global__ __launch_bounds__(256) void transpose4(
    const float* __restrict__ w0, const float* __restrict__ w1,
    const float* __restrict__ w2, const float* __restrict__ w3,
    u16* __restrict__ out)
{
  const float* W = (blockIdx.z==0)?w0:(blockIdx.z==1)?w1:(blockIdx.z==2)?w2:w3;
  u16* O = out + (size_t)blockIdx.z * (1024u*1024u);
  __shared__ __align__(16) u16 T[64*72];
  const int t = threadIdx.x;
  const int r0 = blockIdx.y*64, c0 = blockIdx.x*64;
  #pragma unroll
  for (int i=0;i<2;i++){
    int v = t + i*256;
    int row = v >> 3, col = (v & 7) * 8;
    const float* src = W + (size_t)(r0+row)*NDIM + c0 + col;
    float4 a = *(const float4*)src;
    float4 b = *(const float4*)(src + 4);
    alignas(16) u16 tmp[8];
    tmp[0]=f2b(a.x); tmp[1]=f2b(a.y); tmp[2]=f2b(a.z); tmp[3]=f2b(a.w);
    tmp[4]=f2b(b.x); tmp[5]=f2b(b.y); tmp[6]=f2b(b.z); tmp[7]=f2b(b.w);
    *(uint4*)(T + row*72 + col) = *(const uint4*)tmp;
  }
  __syncthreads();
  #pragma unroll
  for (int i=0;i<2;i++){
    int v = t + i*256;
    int cc = v >> 3, rr = (v & 7) * 8;
    alignas(16) u16 tmp[8];
    #pragma unroll
    for (int j=0;j<8;j++) tmp[j] = T[(rr+j)*72 + cc];
    *(uint4*)(O + (size_t)(c0+cc)*NDIM + r0 + rr) = *(const uint4*)tmp;
  }
}

// ---------------------------------------------------------------------------
// C[M,1024] = A[M,1024] @ B[1024,1024] + bias (fp32 bias), A bf16,
// B given transposed bf16 (BT[n][k]). 128x128 tile, BK=32, 4 waves each
// computing a 64x64 quadrant via 4x4 mfma_f32_16x16x32_bf16.
// Optional interleaved RoPE on cols 0..63 (head 0) for z < rope_mats.
// Output: bf16 (Cb) or fp32 (Cf) per f32_out.
// ---------------------------------------------------------------------------
#define LDA 40   // padded LDS row (32 k-elems + 8 pad), keeps 16B alignment

__global__ __launch_bounds__(256) void gemm_bias_rope(
    const u16* __restrict__ A,     // [M][1024] bf16
    const u16* __restrict__ BT,    // nmats x [1024][1024] bf16 (transposed)
    const float* __restrict__ b0, const float* __restrict__ b1,
    const float* __restrict__ b2,
    u16*   __restrict__ Cb,        // bf16 out (nmats slabs) or null
    float* __restrict__ Cf,        // fp32 out (z==0 only) or null
    const int* __restrict__ pos,
    int M, int rope_mats, int f32_out)
{
  __shared__ __align__(16) u16 As[128*LDA];
  __shared__ __align__(16) u16 Bs[128*LDA];

  const int t    = threadIdx.x;
  const int lane = t & 63;
  const int wave = t >> 6;
  const int z    = blockIdx.z;
  const int m0   = blockIdx.y * 128;
  const int n0   = blockIdx.x * 128;
  const u16* Bm  = BT + (size_t)z * (1024u*1024u);
  u16*       Cm  = Cb ? (Cb + (size_t)z * ((size_t)M * NDIM)) : (u16*)0;
  const float* bias = (z==0) ? b0 : ((z==1) ? b1 : b2);

  const int wm   = (wave >> 1) * 64;
  const int wn   = (wave & 1) * 64;
  const int l15  = lane & 15;
  const int quad = lane >> 4;

  f32x4 acc[4][4];
  #pragma unroll
  for (int i=0;i<4;i++)
    #pragma unroll
    for (int j=0;j<4;j++)
      acc[i][j] = (f32x4){0.f,0.f,0.f,0.f};

  for (int k0 = 0; k0 < 1024; k0 += 32) {
    #pragma unroll
    for (int i=0;i<2;i++){
      int v   = t + i*256;          // 512 16B vectors per 128x32 tile
      int row = v >> 2;
      int col = (v & 3) * 8;
      uint4 av = *(const uint4*)(A  + (size_t)(m0+row)*NDIM + k0 + col);
      uint4 bv = *(const uint4*)(Bm + (size_t)(n0+row)*NDIM + k0 + col);
      *(uint4*)(As + row*LDA + col) = av;
      *(uint4*)(Bs + row*LDA + col) = bv;
    }
    __syncthreads();
    bf16x8 af[4], bfr[4];
    #pragma unroll
    for (int i=0;i<4;i++){
      af[i]  = *(const bf16x8*)(As + (wm + i*16 + l15)*LDA + quad*8);
      bfr[i] = *(const bf16x8*)(Bs + (wn + i*16 + l15)*LDA + quad*8);
    }
    #pragma unroll
    for (int i=0;i<4;i++)
      #pragma unroll
      for (int j=0;j<4;j++)
        acc[i][j] = __builtin_amdgcn_mfma_f32_16x16x32_bf16(
                        af[i], bfr[j], acc[i][j], 0, 0, 0);
    __syncthreads();
  }

  // epilogue: bias (+ RoPE on head-0 cols for Q/K), store
  const bool rope_quadrant = (z < rope_mats) && (n0 == 0) && (wn == 0);
  #pragma unroll
  for (int i=0;i<4;i++){
    const int rbase = m0 + wm + i*16 + quad*4;
    #pragma unroll
    for (int j=0;j<4;j++){
      const int c  = n0 + wn + j*16 + l15;
      const float bv = bias[c];
      f32x4 v4 = acc[i][j];
      #pragma unroll
      for (int r=0;r<4;r++) v4[r] += bv;
      if (rope_quadrant) {
        // interleaved RoPE; pair partner (col c^1) lives in lane^1
        const int   ii  = c >> 1;
        const float inv = powf(10000.0f, -(float)ii * (1.0f/32.0f));
        const float sgn = (c & 1) ? 1.0f : -1.0f;
        #pragma unroll
        for (int r=0;r<4;r++){
          float val     = v4[r];
          float partner = __shfl_xor(val, 1, 64);
          int   srow    = (rbase + r) % S_LEN;
          float ang     = (float)pos[srow] * inv;
          float sv, cv;
          sincosf(ang, &sv, &cv);
          v4[r] = val * cv + sgn * partner * sv;
        }
      }
      if (f32_out) {
        #pragma unroll
        for (int r=0;r<4;r++)
          Cf[(size_t)(rbase + r)*NDIM + c] = v4[r];
      } else {
        #pragma unroll
        for (int r=0;r<4;r++)
          Cm[(size_t)(rbase + r)*NDIM + c] = f2b(v4[r]);
      }
    }
  }
}

// ---------------------------------------------------------------------------
// Block-banded attention. Blocks of 24 queries; allowed keys = blocks
// {qb-1, qb, qb+1} clipped to [0,S): the banded mask is EXACTLY the clipped
// window, so no masking math is needed. One WG per (qblock, head, batch).
// ---------------------------------------------------------------------------
__global__ __launch_bounds__(256) void attn_kernel(
    const u16* __restrict__ q, const u16* __restrict__ k,
    const u16* __restrict__ v, u16* __restrict__ o)
{
  const int qb = blockIdx.x;   // 0..63
  const int h  = blockIdx.y;   // 0..15
  const int b  = blockIdx.z;   // 0..1
  const int t  = threadIdx.x;

  const int ks_ = (qb == 0) ? 0 : (qb - 1) * 24;
  const int ke_ = min(S_LEN, (qb + 2) * 24);
  const int kn  = ke_ - ks_;             // 48 or 72

  __shared__ __align__(16) float Qs[24*64];
  __shared__ __align__(16) u16   Ks[72*64];
  __shared__ __align__(16) u16   Vs[72*64];
  __shared__ __align__(16) float Ss[24*72];

  const size_t qrow0 = (size_t)b*S_LEN + qb*24;
  const size_t krow0 = (size_t)b*S_LEN + ks_;
  const int hoff = h * 64;

  if (t < 192) {                          // Q: 24 rows x 8 vec16
    int row = t >> 3, col = (t & 7) * 8;
    uint4 val = *(const uint4*)(q + (qrow0+row)*NDIM + hoff + col);
    const u16* pu = (const u16*)&val;
    #pragma unroll
    for (int j=0;j<8;j++) Qs[row*64 + col + j] = b2f(pu[j]);
  }
  const int nv = kn * 8;
  for (int e = t; e < nv; e += 256) {
    int row = e >> 3, col = (e & 7) * 8;
    *(uint4*)(Ks + row*64 + col) = *(const uint4*)(k + (krow0+row)*NDIM + hoff + col);
    *(uint4*)(Vs + row*64 + col) = *(const uint4*)(v + (krow0+row)*NDIM + hoff + col);
  }
  __syncthreads();

  // scores = Q K^T * 1/8
  const int ns = 24 * kn;
  for (int e = t; e < ns; e += 256) {
    int qr = e / kn;
    int kk = e - qr * kn;
    const float4* qp = (const float4*)(Qs + qr*64);
    const uint4*  kp = (const uint4*) (Ks + kk*64);
    float sum = 0.f;
    #pragma unroll
    for (int c8 = 0; c8 < 8; c8++) {
      uint4 kv = kp[c8];
      const u16* ku = (const u16*)&kv;
      float4 q0 = qp[c8*2], q1 = qp[c8*2 + 1];
      sum += q0.x*b2f(ku[0]) + q0.y*b2f(ku[1]) + q0.z*b2f(ku[2]) + q0.w*b2f(ku[3])
           + q1.x*b2f(ku[4]) + q1.y*b2f(ku[5]) + q1.z*b2f(ku[6]) + q1.w*b2f(ku[7]);
    }
    Ss[qr*72 + kk] = sum * 0.125f;
  }
  __syncthreads();

  // softmax per query row (24 rows)
  if (t < 24) {
    float m = -1e30f;
    for (int kk = 0; kk < kn; kk++) m = fmaxf(m, Ss[t*72 + kk]);
    float ssum = 0.f;
    for (int kk = 0; kk < kn; kk++) {
      float e0 = __expf(Ss[t*72 + kk] - m);
      Ss[t*72 + kk] = e0;
      ssum += e0;
    }
    float inv = 1.0f / ssum;
    for (int kk = 0; kk < kn; kk++) Ss[t*72 + kk] *= inv;
  }
  __syncthreads();

  // O = P V  (24x64 outputs)
  #pragma unroll
  for (int i=0;i<6;i++){
    int e = t + i*256;
    int row = e >> 6, col = e & 63;
    float sum = 0.f;
    for (int kk = 0; kk < kn; kk++)
      sum += Ss[row*72 + kk] * b2f(Vs[kk*64 + col]);
    o[(qrow0 + row)*NDIM + hoff + col] = f2b(sum);
  }
}

// ---------------------------------------------------------------------------
extern "C" void kernel_launch(void* const* d_in, const int* in_sizes, int n_in,
                              void* d_out, int out_size, void* d_ws, size_t ws_size,
                              hipStream_t stream)
{
  const float* x   = (const float*)d_in[0];
  const float* Wq  = (const float*)d_in[1];
  const float* bq  = (const float*)d_in[2];
  const float* Wk  = (const float*)d_in[3];
  const float* bk  = (const float*)d_in[4];
  const float* Wv  = (const float*)d_in[5];
  const float* bv  = (const float*)d_in[6];
  const float* Wo  = (const float*)d_in[7];
  const float* bo  = (const float*)d_in[8];
  const int*   pos = (const int*)d_in[9];

  u16* ws   = (u16*)d_ws;
  u16* WT   = ws;                               // 4 * 1M elems (8 MiB)
  u16* xb   = WT + 4u*1024u*1024u;              // 3072*1024 elems (6 MiB)
  u16* qkv  = xb + (size_t)MROWS*NDIM;          // 3 * 3072*1024 elems (18 MiB)
  u16* attn = WT;                               // overlay Wq/Wk/Wv^T slots (6 MiB)
  float* outf = (float*)d_out;                  // fp32 [3072][1024]

  cast_f32_bf16<<<dim3(MROWS*NDIM/(256*8)), 256, 0, stream>>>(x, xb);
  transpose4<<<dim3(16,16,4), 256, 0, stream>>>(Wq, Wk, Wv, Wo, WT);
  gemm_bias_rope<<<dim3(8,24,3), 256, 0, stream>>>(
      xb, WT, bq, bk, bv, qkv, nullptr, pos, MROWS, /*rope_mats=*/2, /*f32_out=*/0);
  attn_kernel<<<dim3(64,16,2), 256, 0, stream>>>(
      qkv, qkv + (size_t)MROWS*NDIM, qkv + 2u*(size_t)MROWS*NDIM, attn);
  gemm_bias_rope<<<dim3(8,24,1), 256, 0, stream>>>(
      attn, WT + 3u*1024u*1024u, bo, bo, bo, nullptr, outf, pos, MROWS,
      /*rope_mats=*/0, /*f32_out=*/1);
}

// Round 3
// 200.942 us; speedup vs baseline: 1.2254x; 1.2254x over previous
//
#include <hip/hip_runtime.h>
#include <hip/hip_bf16.h>
#include <stdint.h>

typedef _Float16 f16;
typedef _Float16 f16x8 __attribute__((ext_vector_type(8)));
typedef float    f32x4 __attribute__((ext_vector_type(4)));
typedef unsigned short u16;
typedef unsigned int   u32;

#define S_LEN 1536
#define NDIM  1024
#define MROWS 3072

__device__ __forceinline__ u16 f2b(float f){           // fp32 -> bf16 bits (RNE)
  u32 x = __builtin_bit_cast(u32, f);
  u32 r = x + 0x7fffu + ((x >> 16) & 1u);
  return (u16)(r >> 16);
}
__device__ __forceinline__ u16 f2h(float f){           // fp32 -> f16 bits (RNE)
  _Float16 h = (_Float16)f;
  return __builtin_bit_cast(u16, h);
}
__device__ __forceinline__ float h2f(u16 u){
  return (float)__builtin_bit_cast(_Float16, u);
}

// async global->LDS, 16B per lane, LDS dest = wave-uniform base + lane*16
#define GLDS16(g, l) __builtin_amdgcn_global_load_lds( \
    (const __attribute__((address_space(1))) u32*)(const void*)(g), \
    (__attribute__((address_space(3))) u32*)(void*)(l), 16, 0, 0)

// ---------------------------------------------------------------------------
// Cast fp32 -> f16 bits, 8 elems/thread.
// ---------------------------------------------------------------------------
__global__ __launch_bounds__(256) void cast_f32_f16(
    const float* __restrict__ in, u16* __restrict__ out)
{
  const int i = blockIdx.x * 256 + threadIdx.x;
  const float4* p = (const float4*)in;
  float4 a = p[i*2], b = p[i*2+1];
  alignas(16) u16 tmp[8];
  tmp[0]=f2h(a.x); tmp[1]=f2h(a.y); tmp[2]=f2h(a.z); tmp[3]=f2h(a.w);
  tmp[4]=f2h(b.x); tmp[5]=f2h(b.y); tmp[6]=f2h(b.z); tmp[7]=f2h(b.w);
  *(uint4*)(out + (size_t)i*8) = *(const uint4*)tmp;
}

// ---------------------------------------------------------------------------
// Transpose 4 fp32 [1024][1024] matrices -> f16 WT[n][k].
// ---------------------------------------------------------------------------
__global__ __launch_bounds__(256) void transpose4(
    const float* __restrict__ w0, const float* __restrict__ w1,
    const float* __restrict__ w2, const float* __restrict__ w3,
    u16* __restrict__ out)
{
  const float* W = (blockIdx.z==0)?w0:(blockIdx.z==1)?w1:(blockIdx.z==2)?w2:w3;
  u16* O = out + (size_t)blockIdx.z * (1024u*1024u);
  __shared__ __align__(16) u16 T[64*72];
  const int t = threadIdx.x;
  const int r0 = blockIdx.y*64, c0 = blockIdx.x*64;
  #pragma unroll
  for (int i=0;i<2;i++){
    int v = t + i*256;
    int row = v >> 3, col = (v & 7) * 8;
    const float* src = W + (size_t)(r0+row)*NDIM + c0 + col;
    float4 a = *(const float4*)src;
    float4 b = *(const float4*)(src + 4);
    alignas(16) u16 tmp[8];
    tmp[0]=f2h(a.x); tmp[1]=f2h(a.y); tmp[2]=f2h(a.z); tmp[3]=f2h(a.w);
    tmp[4]=f2h(b.x); tmp[5]=f2h(b.y); tmp[6]=f2h(b.z); tmp[7]=f2h(b.w);
    *(uint4*)(T + row*72 + col) = *(const uint4*)tmp;
  }
  __syncthreads();
  #pragma unroll
  for (int i=0;i<2;i++){
    int v = t + i*256;
    int cc = v >> 3, rr = (v & 7) * 8;
    alignas(16) u16 tmp[8];
    #pragma unroll
    for (int j=0;j<8;j++) tmp[j] = T[(rr+j)*72 + cc];
    *(uint4*)(O + (size_t)(c0+cc)*NDIM + r0 + rr) = *(const uint4*)tmp;
  }
}

// ---------------------------------------------------------------------------
// C[M,1024] = A[M,1024] @ B + bias.  A f16, BT f16 (transposed).
// m97 recipe: global_load_lds width-16 into unpadded [128][32] LDS tiles.
// ---------------------------------------------------------------------------
#define LDT 32

__global__ __launch_bounds__(256) void gemm_bias_rope(
    const u16* __restrict__ A,     // [M][1024] f16
    const u16* __restrict__ BT,    // nmats x [1024][1024] f16 (transposed)
    const float* __restrict__ b0, const float* __restrict__ b1,
    const float* __restrict__ b2,
    u16*   __restrict__ Ch,        // f16 out (nmats slabs) or null
    float* __restrict__ Cf,        // fp32 out (z==0 only) or null
    const int* __restrict__ pos,
    int M, int rope_mats, int f32_out)
{
  __shared__ __align__(16) u16 As[128*LDT];
  __shared__ __align__(16) u16 Bs[128*LDT];

  const int t    = threadIdx.x;
  const int lane = t & 63;
  const int wave = t >> 6;        // 0..3
  const int z    = blockIdx.z;
  const int m0   = blockIdx.y * 128;
  const int n0   = blockIdx.x * 128;
  const u16* Bm  = BT + (size_t)z * (1024u*1024u);
  u16*       Cm  = Ch ? (Ch + (size_t)z * ((size_t)M * NDIM)) : (u16*)0;
  const float* bias = (z==0) ? b0 : ((z==1) ? b1 : b2);

  const int wm   = (wave >> 1) * 64;
  const int wn   = (wave & 1) * 64;
  const int l15  = lane & 15;
  const int quad = lane >> 4;

  // staging: wave covers rows [wave*32, wave*32+32) of each tile;
  // one GLDS16 call = 16 rows (64 lanes x 16B), lane -> (row=lane>>2, col=(lane&3)*8)
  const int lrow = lane >> 2;
  const int lcol = (lane & 3) * 8;
  const u16* gA = A  + (size_t)(m0 + wave*32 + lrow)*NDIM + lcol;
  const u16* gB = Bm + (size_t)(n0 + wave*32 + lrow)*NDIM + lcol;
  u16* lA = As + (wave*32)*LDT;   // wave-uniform LDS bases
  u16* lB = Bs + (wave*32)*LDT;

  f32x4 acc[4][4];
  #pragma unroll
  for (int i=0;i<4;i++)
    #pragma unroll
    for (int j=0;j<4;j++)
      acc[i][j] = (f32x4){0.f,0.f,0.f,0.f};

  for (int k0 = 0; k0 < 1024; k0 += 32) {
    GLDS16(gA + k0,            lA);
    GLDS16(gA + k0 + 16*NDIM,  lA + 16*LDT);
    GLDS16(gB + k0,            lB);
    GLDS16(gB + k0 + 16*NDIM,  lB + 16*LDT);
    __syncthreads();                       // waits vmcnt(0) then barrier
    f16x8 af[4], bfr[4];
    #pragma unroll
    for (int i=0;i<4;i++){
      af[i]  = *(const f16x8*)(As + (wm + i*16 + l15)*LDT + quad*8);
      bfr[i] = *(const f16x8*)(Bs + (wn + i*16 + l15)*LDT + quad*8);
    }
    #pragma unroll
    for (int i=0;i<4;i++)
      #pragma unroll
      for (int j=0;j<4;j++)
        acc[i][j] = __builtin_amdgcn_mfma_f32_16x16x32_f16(
                        af[i], bfr[j], acc[i][j], 0, 0, 0);
    __syncthreads();
  }

  const bool rope_quadrant = (z < rope_mats) && (n0 == 0) && (wn == 0);
  #pragma unroll
  for (int i=0;i<4;i++){
    const int rbase = m0 + wm + i*16 + quad*4;
    #pragma unroll
    for (int j=0;j<4;j++){
      const int c  = n0 + wn + j*16 + l15;
      const float bv = bias[c];
      f32x4 v4 = acc[i][j];
      #pragma unroll
      for (int r=0;r<4;r++) v4[r] += bv;
      if (rope_quadrant) {
        const int   ii  = c >> 1;
        const float inv = powf(10000.0f, -(float)ii * (1.0f/32.0f));
        const float sgn = (c & 1) ? 1.0f : -1.0f;
        #pragma unroll
        for (int r=0;r<4;r++){
          float val     = v4[r];
          float partner = __shfl_xor(val, 1, 64);
          int   srow    = (rbase + r) % S_LEN;
          float ang     = (float)pos[srow] * inv;
          float sv, cv;
          sincosf(ang, &sv, &cv);
          v4[r] = val * cv + sgn * partner * sv;
        }
      }
      if (f32_out) {
        #pragma unroll
        for (int r=0;r<4;r++)
          Cf[(size_t)(rbase + r)*NDIM + c] = v4[r];
      } else {
        #pragma unroll
        for (int r=0;r<4;r++)
          Cm[(size_t)(rbase + r)*NDIM + c] = f2h(v4[r]);
      }
    }
  }
}

// ---------------------------------------------------------------------------
// Block-banded attention, MFMA version. One WG (4 waves) per (qblock, head,
// batch). Banded mask == clipped key window [ks_, ke_): no mask math.
// Scores: Q[24x64] x K^T  via mfma_f32_16x16x32_f16 (A=Q rows, B=K rows —
// identical frag pattern to the verified GEMM). Softmax: wave-parallel
// shuffle reduce. PV: A=P[24 x kn] (f16, LDS), B = Vt[d][key] (V transposed
// into LDS at stage time so B-frags are contiguous in k=key).
// LDS row strides 72/104 u16 (odd multiples of 16B) = minimum bank phases.
// ---------------------------------------------------------------------------
__global__ __launch_bounds__(256) void attn_kernel(
    const u16* __restrict__ q, const u16* __restrict__ k,
    const u16* __restrict__ v, u16* __restrict__ o)
{
  const int qb = blockIdx.x;   // 0..63
  const int h  = blockIdx.y;   // 0..15
  const int b  = blockIdx.z;   // 0..1
  const int t  = threadIdx.x;
  const int lane = t & 63;
  const int wave = t >> 6;     // 0..3
  const int l15  = lane & 15;
  const int quad = lane >> 4;

  const int ks_ = (qb == 0) ? 0 : (qb - 1) * 24;
  const int ke_ = min(S_LEN, (qb + 2) * 24);
  const int kn  = ke_ - ks_;             // 48 or 72

  __shared__ __align__(16) u16   Qs[32*72];    // rows 24..31 garbage (discarded C rows)
  __shared__ __align__(16) u16   Ks[80*72];    // rows kn..79 garbage (discarded C cols)
  __shared__ __align__(16) u16   Vt[64*104];   // V transposed: [d][key], keys kn..95 zeroed
  __shared__ __align__(16) float Ss[32*80];    // scores fp32
  __shared__ __align__(16) u16   Ps[32*104];   // P f16, cols kn..95 zero via softmax store

  const size_t qrow0 = (size_t)b*S_LEN + qb*24;
  const size_t krow0 = (size_t)b*S_LEN + ks_;
  const int hoff = h * 64;

  // ---- stage Q (24x64), K (kn x 64), V transposed (64 x kn) ----
  if (t < 192) {
    int row = t >> 3, col = (t & 7) * 8;
    *(uint4*)(Qs + row*72 + col) = *(const uint4*)(q + (qrow0+row)*NDIM + hoff + col);
  }
  for (int e = t; e < kn*8; e += 256) {
    int row = e >> 3, col = (e & 7) * 8;
    *(uint4*)(Ks + row*72 + col) = *(const uint4*)(k + (krow0+row)*NDIM + hoff + col);
    uint4 vv = *(const uint4*)(v + (krow0+row)*NDIM + hoff + col);
    const u16* pu = (const u16*)&vv;
    #pragma unroll
    for (int j=0;j<8;j++) Vt[(col+j)*104 + row] = pu[j];
  }
  // zero Vt key-pad cols [kn, 96) (NaN hygiene for PV MFMA)
  for (int e = t; e < 64*48; e += 256) {
    int d = e / 48, c = 48 + (e - (e/48)*48);
    if (c >= kn) Vt[d*104 + c] = 0;
  }
  __syncthreads();

  // ---- scores: S = Q K^T * 0.125 ----
  const int ntn = (kn + 15) >> 4;           // 3 or 5 N-tiles of 16 keys
  for (int id = wave; id < 2*ntn; id += 4) {
    int mt = id / ntn, nt = id - (id/ntn)*ntn;
    f32x4 acc = (f32x4){0.f,0.f,0.f,0.f};
    #pragma unroll
    for (int ks2 = 0; ks2 < 2; ks2++) {
      f16x8 a = *(const f16x8*)(Qs + (mt*16 + l15)*72 + ks2*32 + quad*8);
      f16x8 bb= *(const f16x8*)(Ks + (nt*16 + l15)*72 + ks2*32 + quad*8);
      acc = __builtin_amdgcn_mfma_f32_16x16x32_f16(a, bb, acc, 0, 0, 0);
    }
    #pragma unroll
    for (int r=0;r<4;r++)
      Ss[(mt*16 + quad*4 + r)*80 + nt*16 + l15] = acc[r] * 0.125f;
  }
  __syncthreads();

  // ---- softmax, 6 rows per wave, 64-lane shuffle reduce over <=72 cols ----
  #pragma unroll
  for (int i=0;i<6;i++){
    int row = wave*6 + i;
    float v0 = (lane      < kn) ? Ss[row*80 + lane]      : -1e30f;
    float v1 = (lane + 64 < kn) ? Ss[row*80 + 64 + lane] : -1e30f;
    float m = fmaxf(v0, v1);
    #pragma unroll
    for (int off=32; off; off>>=1) m = fmaxf(m, __shfl_xor(m, off, 64));
    float p0 = __expf(v0 - m);
    float p1 = __expf(v1 - m);
    float s = p0 + p1;
    #pragma unroll
    for (int off=32; off; off>>=1) s += __shfl_xor(s, off, 64);
    float inv = 1.0f / s;
    Ps[row*104 + lane] = f2h(p0 * inv);               // cols >= kn get 0
    if (lane < 32) Ps[row*104 + 64 + lane] = f2h(p1 * inv);
  }
  __syncthreads();

  // ---- O = P V : 8 tiles (2 mt x 4 nt), 2 per wave ----
  const int kceil = (kn + 31) >> 5;         // 2 or 3
  #pragma unroll
  for (int id2 = 0; id2 < 2; id2++){
    int id = wave*2 + id2;
    int mt = id >> 2, nt = id & 3;
    f32x4 acc = (f32x4){0.f,0.f,0.f,0.f};
    for (int ks2 = 0; ks2 < kceil; ks2++) {
      f16x8 a = *(const f16x8*)(Ps + (mt*16 + l15)*104 + ks2*32 + quad*8);
      f16x8 bb= *(const f16x8*)(Vt + (nt*16 + l15)*104 + ks2*32 + quad*8);
      acc = __builtin_amdgcn_mfma_f32_16x16x32_f16(a, bb, acc, 0, 0, 0);
    }
    #pragma unroll
    for (int r=0;r<4;r++){
      int row = mt*16 + quad*4 + r;
      if (row < 24)
        o[(qrow0 + row)*NDIM + hoff + nt*16 + l15] = f2h(acc[r]);
    }
  }
}

// ---------------------------------------------------------------------------
extern "C" void kernel_launch(void* const* d_in, const int* in_sizes, int n_in,
                              void* d_out, int out_size, void* d_ws, size_t ws_size,
                              hipStream_t stream)
{
  const float* x   = (const float*)d_in[0];
  const float* Wq  = (const float*)d_in[1];
  const float* bq  = (const float*)d_in[2];
  const float* Wk  = (const float*)d_in[3];
  const float* bk  = (const float*)d_in[4];
  const float* Wv  = (const float*)d_in[5];
  const float* bv  = (const float*)d_in[6];
  const float* Wo  = (const float*)d_in[7];
  const float* bo  = (const float*)d_in[8];
  const int*   pos = (const int*)d_in[9];

  u16* ws   = (u16*)d_ws;
  u16* WT   = ws;                               // 4 * 1M elems (8 MiB)
  u16* xb   = WT + 4u*1024u*1024u;              // 3072*1024 (6 MiB)
  u16* qkv  = xb + (size_t)MROWS*NDIM;          // 3 * 3072*1024 (18 MiB)
  u16* attn = WT;                               // overlay Wq/Wk/Wv^T slabs (6 MiB)
  float* outf = (float*)d_out;                  // fp32 [3072][1024]

  cast_f32_f16<<<dim3(MROWS*NDIM/(256*8)), 256, 0, stream>>>(x, xb);
  transpose4<<<dim3(16,16,4), 256, 0, stream>>>(Wq, Wk, Wv, Wo, WT);
  gemm_bias_rope<<<dim3(8,24,3), 256, 0, stream>>>(
      xb, WT, bq, bk, bv, qkv, nullptr, pos, MROWS, /*rope_mats=*/2, /*f32_out=*/0);
  attn_kernel<<<dim3(64,16,2), 256, 0, stream>>>(
      qkv, qkv + (size_t)MROWS*NDIM, qkv + 2u*(size_t)MROWS*NDIM, attn);
  gemm_bias_rope<<<dim3(8,24,1), 256, 0, stream>>>(
      attn, WT + 3u*1024u*1024u, bo, bo, bo, nullptr, outf, pos, MROWS,
      /*rope_mats=*/0, /*f32_out=*/1);
}

// Round 4
// 179.915 us; speedup vs baseline: 1.3686x; 1.1169x over previous
//
#include <hip/hip_runtime.h>
#include <hip/hip_bf16.h>
#include <stdint.h>

typedef _Float16 f16;
typedef _Float16 f16x8 __attribute__((ext_vector_type(8)));
typedef float    f32x4 __attribute__((ext_vector_type(4)));
typedef unsigned short u16;
typedef unsigned int   u32;

#define S_LEN 1536
#define NDIM  1024
#define MROWS 3072

__device__ __forceinline__ u16 f2h(float f){           // fp32 -> f16 bits (RNE)
  _Float16 h = (_Float16)f;
  return __builtin_bit_cast(u16, h);
}

// async global->LDS, 16B per lane, LDS dest = wave-uniform base + lane*16
#define GLDS16(g, l) __builtin_amdgcn_global_load_lds( \
    (const __attribute__((address_space(1))) u32*)(const void*)(g), \
    (__attribute__((address_space(3))) u32*)(void*)(l), 16, 0, 0)

// ---------------------------------------------------------------------------
// Cast fp32 -> f16 bits, 8 elems/thread.
// ---------------------------------------------------------------------------
__global__ __launch_bounds__(256) void cast_f32_f16(
    const float* __restrict__ in, u16* __restrict__ out)
{
  const int i = blockIdx.x * 256 + threadIdx.x;
  const float4* p = (const float4*)in;
  float4 a = p[i*2], b = p[i*2+1];
  alignas(16) u16 tmp[8];
  tmp[0]=f2h(a.x); tmp[1]=f2h(a.y); tmp[2]=f2h(a.z); tmp[3]=f2h(a.w);
  tmp[4]=f2h(b.x); tmp[5]=f2h(b.y); tmp[6]=f2h(b.z); tmp[7]=f2h(b.w);
  *(uint4*)(out + (size_t)i*8) = *(const uint4*)tmp;
}

// ---------------------------------------------------------------------------
// Transpose 4 fp32 [1024][1024] matrices -> f16 WT[n][k].
// ---------------------------------------------------------------------------
__global__ __launch_bounds__(256) void transpose4(
    const float* __restrict__ w0, const float* __restrict__ w1,
    const float* __restrict__ w2, const float* __restrict__ w3,
    u16* __restrict__ out)
{
  const float* W = (blockIdx.z==0)?w0:(blockIdx.z==1)?w1:(blockIdx.z==2)?w2:w3;
  u16* O = out + (size_t)blockIdx.z * (1024u*1024u);
  __shared__ __align__(16) u16 T[64*72];
  const int t = threadIdx.x;
  const int r0 = blockIdx.y*64, c0 = blockIdx.x*64;
  #pragma unroll
  for (int i=0;i<2;i++){
    int v = t + i*256;
    int row = v >> 3, col = (v & 7) * 8;
    const float* src = W + (size_t)(r0+row)*NDIM + c0 + col;
    float4 a = *(const float4*)src;
    float4 b = *(const float4*)(src + 4);
    alignas(16) u16 tmp[8];
    tmp[0]=f2h(a.x); tmp[1]=f2h(a.y); tmp[2]=f2h(a.z); tmp[3]=f2h(a.w);
    tmp[4]=f2h(b.x); tmp[5]=f2h(b.y); tmp[6]=f2h(b.z); tmp[7]=f2h(b.w);
    *(uint4*)(T + row*72 + col) = *(const uint4*)tmp;
  }
  __syncthreads();
  #pragma unroll
  for (int i=0;i<2;i++){
    int v = t + i*256;
    int cc = v >> 3, rr = (v & 7) * 8;
    alignas(16) u16 tmp[8];
    #pragma unroll
    for (int j=0;j<8;j++) tmp[j] = T[(rr+j)*72 + cc];
    *(uint4*)(O + (size_t)(c0+cc)*NDIM + r0 + rr) = *(const uint4*)tmp;
  }
}

// ---------------------------------------------------------------------------
// C[M,1024] = A[M,1024] @ B + bias.  A f16, BT f16 (transposed).
// Tile 128(M) x 64(N), BK=64 as two [.][32] subtiles (keeps the verified
// unpadded GLDS16 lane-contiguous layout). 4 waves as 2x2: wave quadrant
// 64(m) x 32(n), acc 4x2. Grid: (N/64, M/128, nmats) — 2x the blocks and
// 2x the MFMA-per-barrier of the R3 version (which was latency-bound at
// 2.25 WG/CU, MfmaUtil 12%).
// ---------------------------------------------------------------------------
#define SUBK 32

__global__ __launch_bounds__(256) void gemm_bias_rope(
    const u16* __restrict__ A,     // [M][1024] f16
    const u16* __restrict__ BT,    // nmats x [1024][1024] f16 (transposed)
    const float* __restrict__ b0, const float* __restrict__ b1,
    const float* __restrict__ b2,
    u16*   __restrict__ Ch,        // f16 out (nmats slabs) or null
    float* __restrict__ Cf,        // fp32 out (z==0 only) or null
    const int* __restrict__ pos,
    int M, int rope_mats, int f32_out)
{
  __shared__ __align__(16) u16 As[2*128*SUBK];   // 16 KiB
  __shared__ __align__(16) u16 Bs[2*64*SUBK];    //  8 KiB

  const int t    = threadIdx.x;
  const int lane = t & 63;
  const int wave = t >> 6;        // 0..3
  const int z    = blockIdx.z;
  const int m0   = blockIdx.y * 128;
  const int n0   = blockIdx.x * 64;
  const u16* Bm  = BT + (size_t)z * (1024u*1024u);
  u16*       Cm  = Ch ? (Ch + (size_t)z * ((size_t)M * NDIM)) : (u16*)0;
  const float* bias = (z==0) ? b0 : ((z==1) ? b1 : b2);

  const int wm   = (wave >> 1) * 64;   // {0,64}
  const int wn   = (wave & 1) * 32;    // {0,32}
  const int l15  = lane & 15;
  const int quad = lane >> 4;

  // staging lane map: one GLDS16 = 16 rows x 32 cols (64 lanes x 16B)
  const int lrow = lane >> 2;
  const int lcol = (lane & 3) * 8;
  const u16* gA = A  + (size_t)(m0 + wave*32 + lrow)*NDIM + lcol; // 32 rows/wave
  const u16* gB = Bm + (size_t)(n0 + wave*16 + lrow)*NDIM + lcol; // 16 rows/wave
  u16* lA = As + (wave*32)*SUBK;   // wave-uniform LDS bases (subtile 0)
  u16* lB = Bs + (wave*16)*SUBK;

  f32x4 acc[4][2];
  #pragma unroll
  for (int i=0;i<4;i++)
    #pragma unroll
    for (int j=0;j<2;j++)
      acc[i][j] = (f32x4){0.f,0.f,0.f,0.f};

  for (int k0 = 0; k0 < 1024; k0 += 64) {
    #pragma unroll
    for (int kb=0;kb<2;kb++){
      const u16* ga = gA + k0 + kb*SUBK;
      u16* la = lA + kb*(128*SUBK);
      GLDS16(ga,           la);
      GLDS16(ga + 16*NDIM, la + 16*SUBK);
      GLDS16(gB + k0 + kb*SUBK, lB + kb*(64*SUBK));
    }
    __syncthreads();                       // vmcnt(0) drain + barrier
    #pragma unroll
    for (int kb=0;kb<2;kb++){
      f16x8 af[4], bfr[2];
      #pragma unroll
      for (int i=0;i<4;i++)
        af[i]  = *(const f16x8*)(As + kb*(128*SUBK) + (wm + i*16 + l15)*SUBK + quad*8);
      #pragma unroll
      for (int j=0;j<2;j++)
        bfr[j] = *(const f16x8*)(Bs + kb*(64*SUBK)  + (wn + j*16 + l15)*SUBK + quad*8);
      #pragma unroll
      for (int i=0;i<4;i++)
        #pragma unroll
        for (int j=0;j<2;j++)
          acc[i][j] = __builtin_amdgcn_mfma_f32_16x16x32_f16(
                          af[i], bfr[j], acc[i][j], 0, 0, 0);
    }
    __syncthreads();
  }

  // epilogue: bias (+ RoPE on cols 0..63 = head 0, tile n0==0) and store
  const bool rope_tile = (z < rope_mats) && (n0 == 0);
  #pragma unroll
  for (int i=0;i<4;i++){
    const int rbase = m0 + wm + i*16 + quad*4;
    #pragma unroll
    for (int j=0;j<2;j++){
      const int c  = n0 + wn + j*16 + l15;
      const float bv = bias[c];
      f32x4 v4 = acc[i][j];
      #pragma unroll
      for (int r=0;r<4;r++) v4[r] += bv;
      if (rope_tile) {
        const int   ii  = c >> 1;
        const float inv = powf(10000.0f, -(float)ii * (1.0f/32.0f));
        const float sgn = (c & 1) ? 1.0f : -1.0f;
        #pragma unroll
        for (int r=0;r<4;r++){
          float val     = v4[r];
          float partner = __shfl_xor(val, 1, 64);   // col c^1 lives in lane^1
          int   srow    = (rbase + r) % S_LEN;
          float ang     = (float)pos[srow] * inv;
          float sv, cv;
          sincosf(ang, &sv, &cv);
          v4[r] = val * cv + sgn * partner * sv;
        }
      }
      if (f32_out) {
        #pragma unroll
        for (int r=0;r<4;r++)
          Cf[(size_t)(rbase + r)*NDIM + c] = v4[r];
      } else {
        #pragma unroll
        for (int r=0;r<4;r++)
          Cm[(size_t)(rbase + r)*NDIM + c] = f2h(v4[r]);
      }
    }
  }
}

// ---------------------------------------------------------------------------
// Block-banded attention, MFMA version (unchanged from R3 — passed; will
// re-examine when it tops the profile).
// ---------------------------------------------------------------------------
__global__ __launch_bounds__(256) void attn_kernel(
    const u16* __restrict__ q, const u16* __restrict__ k,
    const u16* __restrict__ v, u16* __restrict__ o)
{
  const int qb = blockIdx.x;   // 0..63
  const int h  = blockIdx.y;   // 0..15
  const int b  = blockIdx.z;   // 0..1
  const int t  = threadIdx.x;
  const int lane = t & 63;
  const int wave = t >> 6;     // 0..3
  const int l15  = lane & 15;
  const int quad = lane >> 4;

  const int ks_ = (qb == 0) ? 0 : (qb - 1) * 24;
  const int ke_ = min(S_LEN, (qb + 2) * 24);
  const int kn  = ke_ - ks_;             // 48 or 72

  __shared__ __align__(16) u16   Qs[32*72];
  __shared__ __align__(16) u16   Ks[80*72];
  __shared__ __align__(16) u16   Vt[64*104];
  __shared__ __align__(16) float Ss[32*80];
  __shared__ __align__(16) u16   Ps[32*104];

  const size_t qrow0 = (size_t)b*S_LEN + qb*24;
  const size_t krow0 = (size_t)b*S_LEN + ks_;
  const int hoff = h * 64;

  if (t < 192) {
    int row = t >> 3, col = (t & 7) * 8;
    *(uint4*)(Qs + row*72 + col) = *(const uint4*)(q + (qrow0+row)*NDIM + hoff + col);
  }
  for (int e = t; e < kn*8; e += 256) {
    int row = e >> 3, col = (e & 7) * 8;
    *(uint4*)(Ks + row*72 + col) = *(const uint4*)(k + (krow0+row)*NDIM + hoff + col);
    uint4 vv = *(const uint4*)(v + (krow0+row)*NDIM + hoff + col);
    const u16* pu = (const u16*)&vv;
    #pragma unroll
    for (int j=0;j<8;j++) Vt[(col+j)*104 + row] = pu[j];
  }
  for (int e = t; e < 64*48; e += 256) {
    int d = e / 48, c = 48 + (e - (e/48)*48);
    if (c >= kn) Vt[d*104 + c] = 0;
  }
  __syncthreads();

  const int ntn = (kn + 15) >> 4;
  for (int id = wave; id < 2*ntn; id += 4) {
    int mt = id / ntn, nt = id - (id/ntn)*ntn;
    f32x4 acc = (f32x4){0.f,0.f,0.f,0.f};
    #pragma unroll
    for (int ks2 = 0; ks2 < 2; ks2++) {
      f16x8 a = *(const f16x8*)(Qs + (mt*16 + l15)*72 + ks2*32 + quad*8);
      f16x8 bb= *(const f16x8*)(Ks + (nt*16 + l15)*72 + ks2*32 + quad*8);
      acc = __builtin_amdgcn_mfma_f32_16x16x32_f16(a, bb, acc, 0, 0, 0);
    }
    #pragma unroll
    for (int r=0;r<4;r++)
      Ss[(mt*16 + quad*4 + r)*80 + nt*16 + l15] = acc[r] * 0.125f;
  }
  __syncthreads();

  #pragma unroll
  for (int i=0;i<6;i++){
    int row = wave*6 + i;
    float v0 = (lane      < kn) ? Ss[row*80 + lane]      : -1e30f;
    float v1 = (lane + 64 < kn) ? Ss[row*80 + 64 + lane] : -1e30f;
    float m = fmaxf(v0, v1);
    #pragma unroll
    for (int off=32; off; off>>=1) m = fmaxf(m, __shfl_xor(m, off, 64));
    float p0 = __expf(v0 - m);
    float p1 = __expf(v1 - m);
    float s = p0 + p1;
    #pragma unroll
    for (int off=32; off; off>>=1) s += __shfl_xor(s, off, 64);
    float inv = 1.0f / s;
    Ps[row*104 + lane] = f2h(p0 * inv);
    if (lane < 32) Ps[row*104 + 64 + lane] = f2h(p1 * inv);
  }
  __syncthreads();

  const int kceil = (kn + 31) >> 5;
  #pragma unroll
  for (int id2 = 0; id2 < 2; id2++){
    int id = wave*2 + id2;
    int mt = id >> 2, nt = id & 3;
    f32x4 acc = (f32x4){0.f,0.f,0.f,0.f};
    for (int ks2 = 0; ks2 < kceil; ks2++) {
      f16x8 a = *(const f16x8*)(Ps + (mt*16 + l15)*104 + ks2*32 + quad*8);
      f16x8 bb= *(const f16x8*)(Vt + (nt*16 + l15)*104 + ks2*32 + quad*8);
      acc = __builtin_amdgcn_mfma_f32_16x16x32_f16(a, bb, acc, 0, 0, 0);
    }
    #pragma unroll
    for (int r=0;r<4;r++){
      int row = mt*16 + quad*4 + r;
      if (row < 24)
        o[(qrow0 + row)*NDIM + hoff + nt*16 + l15] = f2h(acc[r]);
    }
  }
}

// ---------------------------------------------------------------------------
extern "C" void kernel_launch(void* const* d_in, const int* in_sizes, int n_in,
                              void* d_out, int out_size, void* d_ws, size_t ws_size,
                              hipStream_t stream)
{
  const float* x   = (const float*)d_in[0];
  const float* Wq  = (const float*)d_in[1];
  const float* bq  = (const float*)d_in[2];
  const float* Wk  = (const float*)d_in[3];
  const float* bk  = (const float*)d_in[4];
  const float* Wv  = (const float*)d_in[5];
  const float* bv  = (const float*)d_in[6];
  const float* Wo  = (const float*)d_in[7];
  const float* bo  = (const float*)d_in[8];
  const int*   pos = (const int*)d_in[9];

  u16* ws   = (u16*)d_ws;
  u16* WT   = ws;                               // 4 * 1M elems (8 MiB)
  u16* xb   = WT + 4u*1024u*1024u;              // 3072*1024 (6 MiB)
  u16* qkv  = xb + (size_t)MROWS*NDIM;          // 3 * 3072*1024 (18 MiB)
  u16* attn = WT;                               // overlay Wq/Wk/Wv^T slabs (6 MiB)
  float* outf = (float*)d_out;                  // fp32 [3072][1024]

  cast_f32_f16<<<dim3(MROWS*NDIM/(256*8)), 256, 0, stream>>>(x, xb);
  transpose4<<<dim3(16,16,4), 256, 0, stream>>>(Wq, Wk, Wv, Wo, WT);
  gemm_bias_rope<<<dim3(16,24,3), 256, 0, stream>>>(
      xb, WT, bq, bk, bv, qkv, nullptr, pos, MROWS, /*rope_mats=*/2, /*f32_out=*/0);
  attn_kernel<<<dim3(64,16,2), 256, 0, stream>>>(
      qkv, qkv + (size_t)MROWS*NDIM, qkv + 2u*(size_t)MROWS*NDIM, attn);
  gemm_bias_rope<<<dim3(16,24,1), 256, 0, stream>>>(
      attn, WT + 3u*1024u*1024u, bo, bo, bo, nullptr, outf, pos, MROWS,
      /*rope_mats=*/0, /*f32_out=*/1);
}